// Round 14
// baseline (250.671 us; speedup 1.0000x reference)
//
#include <hip/hip_runtime.h>

typedef int i32x4 __attribute__((ext_vector_type(4)));

#define AS1 __attribute__((address_space(1)))
#define AS3 __attribute__((address_space(3)))

#define M_DIM 8192
#define N_DIM 8192
#define K_DIM 2048
#define NT 32   // K-tiles of 64 bytes

// ---------------- quantize x: per-tensor scale, 16 elems/thread ----------------
__global__ __launch_bounds__(256) void quant_x_kernel(
    const float* __restrict__ x, const float* __restrict__ in_scale,
    i32x4* __restrict__ qx, int n16)
{
    int idx = blockIdx.x * 256 + threadIdx.x;
    if (idx >= n16) return;
    float s = in_scale[0];
    const float4* xp = reinterpret_cast<const float4*>(x) + (size_t)idx * 4;
    union { char c[16]; i32x4 v; } u;
#pragma unroll
    for (int v4 = 0; v4 < 4; ++v4) {
        float4 f = xp[v4];
        u.c[v4*4+0] = (char)(int)fminf(fmaxf(rintf(f.x / s), -128.f), 127.f);
        u.c[v4*4+1] = (char)(int)fminf(fmaxf(rintf(f.y / s), -128.f), 127.f);
        u.c[v4*4+2] = (char)(int)fminf(fmaxf(rintf(f.z / s), -128.f), 127.f);
        u.c[v4*4+3] = (char)(int)fminf(fmaxf(rintf(f.w / s), -128.f), 127.f);
    }
    qx[idx] = u.v;
}

// ---------------- quantize w: per-row (out-channel) scale ----------------
__global__ __launch_bounds__(256) void quant_w_kernel(
    const float* __restrict__ w, const float* __restrict__ w_scale,
    i32x4* __restrict__ qw, int n16)
{
    int idx = blockIdx.x * 256 + threadIdx.x;
    if (idx >= n16) return;
    float s = w_scale[idx >> 7];   // K=2048 -> 128 threads (of 16 elems) per row
    const float4* wp = reinterpret_cast<const float4*>(w) + (size_t)idx * 4;
    union { char c[16]; i32x4 v; } u;
#pragma unroll
    for (int v4 = 0; v4 < 4; ++v4) {
        float4 f = wp[v4];
        u.c[v4*4+0] = (char)(int)fminf(fmaxf(rintf(f.x / s), -128.f), 127.f);
        u.c[v4*4+1] = (char)(int)fminf(fmaxf(rintf(f.y / s), -128.f), 127.f);
        u.c[v4*4+2] = (char)(int)fminf(fmaxf(rintf(f.z / s), -128.f), 127.f);
        u.c[v4*4+3] = (char)(int)fminf(fmaxf(rintf(f.w / s), -128.f), 127.f);
    }
    qw[idx] = u.v;
}

// ---------------- per-out-channel combined scale + dequantized bias ----------------
__global__ __launch_bounds__(256) void prep_kernel(
    const float* __restrict__ bias, const float* __restrict__ in_scale,
    const float* __restrict__ w_scale, const float* __restrict__ b_scale,
    float* __restrict__ oscale, float* __restrict__ obias, int n)
{
    int i = blockIdx.x * 256 + threadIdx.x;
    if (i >= n) return;
    oscale[i] = in_scale[0] * w_scale[i] * 0.5f;   // W_ALPHA
    float bs = b_scale[i];
    float q = fminf(fmaxf(rintf(bias[i] / bs), -128.f), 127.f);
    obias[i] = q * bs * 0.75f;                      // B_BETA
}

// ---------------- int8 GEMM: 128x256, 8 waves of 64x64, 2 blocks/CU, 3-deep ring ----------
// R11 (182us, best) + counted-vmcnt upgrade. R11's identified stall: per-tile
// vmcnt(0) waits on loads issued at the top of the SAME tile (~450cy cover vs
// 300-900cy latency). Fix: 3-deep ring; stage(t+2) issued during tile t; gate
// vmcnt(3) retires stage(t+1) (issued one FULL tile ago, ~850+cy cover) while
// stage(t+2)'s 3 calls stay in flight across the barrier (T4: never drain to 0).
// LDS: 3 bufs x (A 8KB + B 16KB) = 72 KiB -> 2 blocks/CU = 144 <= 160. Registers
// ~124 (60 + 64 acc) at launch_bounds(512,4) -> 4 waves/SIMD from 2 independent
// blocks (the R11 win ingredient; R13 proved wave count > LDS ratio).
// Swizzle (R2-verified, 0 conflicts): slot' = slot ^ ((row>>1)&3), inverse-swizzled
// global source + linear global_load_lds dest (rule 21).
// Ring safety: tile t reads buf t%3; stage(t+2) writes buf (t+2)%3 = (t-1)%3, whose
// readers all passed tile t-1's closing barrier before stage(t+2) issues.
__global__ __launch_bounds__(512, 4) void gemm_i8_kernel(
    const char* __restrict__ qx,   // [M][K] int8
    const char* __restrict__ qw,   // [N][K] int8
    const float* __restrict__ oscale,
    const float* __restrict__ obias,
    float* __restrict__ out)       // [M][N] fp32
{
    __shared__ __align__(16) char ldsA[3 * 8192];
    __shared__ __align__(16) char ldsB[3 * 16384];

    const int t    = threadIdx.x;          // 0..511
    const int lane = t & 63;
    const int wid  = t >> 6;               // 0..7
    const int wm   = wid >> 2;             // 0..1 (64-row block of 128)
    const int wn   = wid & 3;              // 0..3 (64-col block of 256)

    // XCD-aware swizzle: 2048 blocks, 2048 % 8 == 0 -> bijective
    int bid = blockIdx.x;
    int sid = (bid & 7) * 256 + (bid >> 3);
    const size_t brow = (size_t)(sid >> 5) * 128;   // 64 M-tiles
    const size_t bcol = (size_t)(sid & 31) * 256;   // 32 N-tiles

    // staging: per call 512 threads cover 128 rows x 64 B. Thread t: row t>>2
    // (B call 1: +128), 16B slot t&3 (linear dest). Global source pre-swizzled:
    // logical slot = (t&3) ^ ((row>>1)&3) = (t&3) ^ ((t>>3)&3)  [invariant under +128].
    const int srow  = t >> 2;              // 0..127
    const int lslot = (t & 3) ^ ((t >> 3) & 3);
    const char* gA = qx + (brow + srow) * K_DIM + lslot * 16;
    const char* gB = qw + (bcol + srow) * K_DIM + lslot * 16;
    char* dstA = ldsA + t * 16;
    char* dstB = ldsB + t * 16;

    // STAGE(tile, buf): 3 global_load_lds calls into ring slot buf.
#define STAGE(tt_, bb_) do {                                                              \
    const int ko_ = (tt_) * 64;                                                           \
    __builtin_amdgcn_global_load_lds((const AS1 unsigned int*)(gA + ko_),                 \
        (AS3 unsigned int*)(dstA + (bb_) * 8192), 16, 0, 0);                              \
    __builtin_amdgcn_global_load_lds((const AS1 unsigned int*)(gB + ko_),                 \
        (AS3 unsigned int*)(dstB + (bb_) * 16384), 16, 0, 0);                             \
    __builtin_amdgcn_global_load_lds((const AS1 unsigned int*)(gB + ko_ + 128 * K_DIM),   \
        (AS3 unsigned int*)(dstB + (bb_) * 16384 + 8192), 16, 0, 0);                      \
  } while (0)

    // frag read offsets (swizzled): row r, slot kg ^ ((r>>1)&3); frag step = 16
    // rows = +1024 B (swizzle-invariant).
    const int lrow = lane & 15;
    const int kg   = lane >> 4;            // 16B k-group 0..3
    const int rA   = wm * 64 + lrow;
    const int rB   = wn * 64 + lrow;
    const int offA0 = rA * 64 + ((kg ^ ((rA >> 1) & 3)) * 16);
    const int offB0 = rB * 64 + ((kg ^ ((rB >> 1) & 3)) * 16);

    i32x4 acc[4][4];
#pragma unroll
    for (int m = 0; m < 4; ++m)
#pragma unroll
        for (int n = 0; n < 4; ++n)
            acc[m][n] = (i32x4){0, 0, 0, 0};

#define MM(m_, n_, a_, b_) acc[m_][n_] = __builtin_amdgcn_mfma_i32_16x16x64_i8((a_), (b_), acc[m_][n_], 0, 0, 0)
#define BAR() do { __builtin_amdgcn_s_barrier(); asm volatile("" ::: "memory"); } while (0)
#define VMC3() asm volatile("s_waitcnt vmcnt(3)" ::: "memory")
#define VMC0() asm volatile("s_waitcnt vmcnt(0)" ::: "memory")

    // KT(tile, curbuf, nxtbuf, PF_, GATE_): GATE_ 0 = vmcnt(3)+BAR (steady, leaves
    // stage(t+2) in flight), 1 = vmcnt(0)+BAR (tile 30), 2 = none (tile 31).
#define KT(tt_, cb_, nb_, PF_, GATE_) do {                                                \
    const char* bA = ldsA + (cb_) * 8192;                                                 \
    const char* bB = ldsB + (cb_) * 16384;                                                \
    if (PF_) STAGE((tt_) + 2, nb_);                                                       \
    i32x4 a0 = *(const i32x4*)(bA + offA0);                                               \
    i32x4 a1 = *(const i32x4*)(bA + offA0 + 1024);                                        \
    i32x4 a2 = *(const i32x4*)(bA + offA0 + 2048);                                        \
    i32x4 a3 = *(const i32x4*)(bA + offA0 + 3072);                                        \
    i32x4 b0 = *(const i32x4*)(bB + offB0);                                               \
    i32x4 b1 = *(const i32x4*)(bB + offB0 + 1024);                                        \
    i32x4 b2 = *(const i32x4*)(bB + offB0 + 2048);                                        \
    i32x4 b3 = *(const i32x4*)(bB + offB0 + 3072);                                        \
    __builtin_amdgcn_s_setprio(1);                                                        \
    MM(0,0,a0,b0); MM(0,1,a0,b1); MM(0,2,a0,b2); MM(0,3,a0,b3);                           \
    MM(1,0,a1,b0); MM(1,1,a1,b1); MM(1,2,a1,b2); MM(1,3,a1,b3);                           \
    MM(2,0,a2,b0); MM(2,1,a2,b1); MM(2,2,a2,b2); MM(2,3,a2,b3);                           \
    MM(3,0,a3,b0); MM(3,1,a3,b1); MM(3,2,a3,b2); MM(3,3,a3,b3);                           \
    __builtin_amdgcn_s_setprio(0);                                                        \
    if ((GATE_) == 0)      { VMC3(); BAR(); }                                             \
    else if ((GATE_) == 1) { VMC0(); BAR(); }                                             \
  } while (0)

    // prologue: stage tiles 0,1; vmcnt(3) retires stage(0), leaves stage(1) in
    // flight; barrier certifies buf 0.
    STAGE(0, 0);
    STAGE(1, 1);
    VMC3();
    BAR();

    // steady state: tiles 0..29 in groups of 3 (buffer indices compile-time).
    // Ledger at tile t's gate: outstanding = stage(t+1) 3 + stage(t+2) 3 = 6;
    // vmcnt(3) retires stage(t+1) (issued one full tile ago); barrier certifies it.
    for (int it = 0; it < 10; ++it) {
        KT(3*it,     0, 2, 1, 0);
        KT(3*it + 1, 1, 0, 1, 0);
        KT(3*it + 2, 2, 1, 1, 0);
    }
    // tail: tile 30 (buf 0; stage(31) already in flight from tile 29 -> drain all),
    // tile 31 (buf 1; nothing outstanding).
    KT(30, 0, 2, 0, 1);
    KT(31, 1, 2, 0, 2);

#undef KT
#undef STAGE
#undef MM
#undef BAR
#undef VMC3
#undef VMC0

    // epilogue: C/D layout col = lane&15, row = (lane>>4)*4 + j
    const int colq = lane & 15;
    const int rowq = lane >> 4;
#pragma unroll
    for (int n = 0; n < 4; ++n) {
        size_t col = bcol + wn * 64 + n * 16 + colq;
        float sc = oscale[col];
        float bi = obias[col];
#pragma unroll
        for (int m = 0; m < 4; ++m) {
            size_t rbase = brow + wm * 64 + m * 16 + (size_t)rowq * 4;
#pragma unroll
            for (int j = 0; j < 4; ++j)
                out[(rbase + j) * N_DIM + col] = (float)acc[m][n][j] * sc + bi;
        }
    }
}

extern "C" void kernel_launch(void* const* d_in, const int* in_sizes, int n_in,
                              void* d_out, int out_size, void* d_ws, size_t ws_size,
                              hipStream_t stream) {
    const float* x        = (const float*)d_in[0];
    const float* weight   = (const float*)d_in[1];
    const float* bias     = (const float*)d_in[2];
    const float* in_scale = (const float*)d_in[3];
    const float* w_scale  = (const float*)d_in[4];
    const float* b_scale  = (const float*)d_in[5];
    float* out = (float*)d_out;

    char* ws = (char*)d_ws;
    const size_t xk = (size_t)M_DIM * K_DIM;
    const size_t wk = (size_t)N_DIM * K_DIM;
    char*  qx     = ws;
    char*  qw     = ws + xk;
    float* oscale = (float*)(ws + xk + wk);
    float* obias  = oscale + N_DIM;

    const int n16 = (int)(xk / 16);   // 1,048,576 = 4096 * 256
    quant_x_kernel<<<4096, 256, 0, stream>>>(x, in_scale, (i32x4*)qx, n16);
    quant_w_kernel<<<4096, 256, 0, stream>>>(weight, w_scale, (i32x4*)qw, n16);
    prep_kernel<<<32, 256, 0, stream>>>(bias, in_scale, w_scale, b_scale, oscale, obias, N_DIM);

    gemm_i8_kernel<<<2048, 512, 0, stream>>>(qx, qw, oscale, obias, out);
}

// Round 15
// 218.724 us; speedup vs baseline: 1.1461x; 1.1461x over previous
//
#include <hip/hip_runtime.h>

typedef int i32x4 __attribute__((ext_vector_type(4)));

#define AS1 __attribute__((address_space(1)))
#define AS3 __attribute__((address_space(3)))

#define M_DIM 8192
#define N_DIM 8192
#define K_DIM 2048
#define NT 32   // K-tiles of 64 bytes

// ---------------- fused quantize: x (per-tensor), w (per-row), prep (scale+bias) -------
// blocks [0,4096): x; [4096,8192): w; [8192,8224): oscale/obias prep.
__global__ __launch_bounds__(256) void quant_all_kernel(
    const float* __restrict__ x, const float* __restrict__ w,
    const float* __restrict__ bias,
    const float* __restrict__ in_scale, const float* __restrict__ w_scale,
    const float* __restrict__ b_scale,
    i32x4* __restrict__ qx, i32x4* __restrict__ qw,
    float* __restrict__ oscale, float* __restrict__ obias)
{
    const int bid = blockIdx.x;
    if (bid < 8192) {
        const int idx = (bid & 4095) * 256 + threadIdx.x;   // 0..1048575
        const bool isx = bid < 4096;
        float s = isx ? in_scale[0] : w_scale[idx >> 7];
        const float4* p = reinterpret_cast<const float4*>(isx ? x : w) + (size_t)idx * 4;
        union { char c[16]; i32x4 v; } u;
#pragma unroll
        for (int v4 = 0; v4 < 4; ++v4) {
            float4 f = p[v4];
            u.c[v4*4+0] = (char)(int)fminf(fmaxf(rintf(f.x / s), -128.f), 127.f);
            u.c[v4*4+1] = (char)(int)fminf(fmaxf(rintf(f.y / s), -128.f), 127.f);
            u.c[v4*4+2] = (char)(int)fminf(fmaxf(rintf(f.z / s), -128.f), 127.f);
            u.c[v4*4+3] = (char)(int)fminf(fmaxf(rintf(f.w / s), -128.f), 127.f);
        }
        (isx ? qx : qw)[idx] = u.v;
    } else {
        const int i = (bid - 8192) * 256 + threadIdx.x;
        if (i < N_DIM) {
            oscale[i] = in_scale[0] * w_scale[i] * 0.5f;   // W_ALPHA
            float bs = b_scale[i];
            float q = fminf(fmaxf(rintf(bias[i] / bs), -128.f), 127.f);
            obias[i] = q * bs * 0.75f;                      // B_BETA
        }
    }
}

// ---------------- int8 GEMM: 128x128 tile, 4 waves of 64x64, 4 blocks/CU ----------------
// R11 (182us) pushed to 4-way block independence: each SIMD holds 4 waves from 4
// DIFFERENT blocks (only 4 waves barrier-lock together vs R11's 8) -> every stall
// of one block covered by three others (m114). Regs ~124 <= 128 at bounds(256,4);
// LDS 2 bufs x (A 8KB + B 8KB) = 32 KiB <= 40. Per-wave 64x64 (acc=64), the
// R2/R11-verified 16-row/4-slot swizzle read pattern -> 0 conflicts.
// L2: R12's column-stripe XCD swizzle (concurrent 128 blocks/XCD = 16 rows x 8
// cols; B stripe = 2MB L2-resident) — R14 showed FETCH blowup kills wins.
// Schedule = R11's proven loop: {stage(t+1); 8 ds_read; 16 MFMA; vmcnt(0); bar}.
__global__ __launch_bounds__(256, 4) void gemm_i8_kernel(
    const char* __restrict__ qx,   // [M][K] int8
    const char* __restrict__ qw,   // [N][K] int8
    const float* __restrict__ oscale,
    const float* __restrict__ obias,
    float* __restrict__ out)       // [M][N] fp32
{
    __shared__ __align__(16) char ldsA[2 * 8192];
    __shared__ __align__(16) char ldsB[2 * 8192];

    const int t    = threadIdx.x;          // 0..255
    const int lane = t & 63;
    const int wid  = t >> 6;               // 0..3
    const int wm   = wid >> 1;             // 0..1
    const int wn   = wid & 1;              // 0..1

    // XCD column-stripe swizzle (R12-proven locality): xcd = bid&7 owns col-blocks
    // [xcd*8, xcd*8+8); within XCD iterate cols-fastest (concurrent ~128 blocks =
    // 16 rows x 8 cols -> A 4MB, B 2MB working set).
    int bid = blockIdx.x;                   // 4096 blocks
    int sl  = bid >> 3;                     // 0..511
    const size_t brow = (size_t)(sl >> 3) * 128;                    // 64 row-blocks
    const size_t bcol = (size_t)((bid & 7) * 8 + (sl & 7)) * 128;   // 64 col-blocks

    // staging: per call 256 threads cover 64 rows x 64 B (4KB). Thread t: row
    // c*64 + t/4, 16B slot t&3 (linear dest). Global source pre-swizzled:
    // logical slot = (t&3) ^ ((row>>1)&3) = (t&3) ^ ((t>>3)&3)  [invariant under +64].
    const int srow  = t >> 2;              // 0..63
    const int lslot = (t & 3) ^ ((t >> 3) & 3);
    const char* gA = qx + (brow + srow) * K_DIM + lslot * 16;
    const char* gB = qw + (bcol + srow) * K_DIM + lslot * 16;
    char* dstA = ldsA + t * 16;
    char* dstB = ldsB + t * 16;

#define STAGE(tt_) do {                                                                   \
    const int bb_ = ((tt_) & 1) * 8192; const int ko_ = (tt_) * 64;                       \
    __builtin_amdgcn_global_load_lds((const AS1 unsigned int*)(gA + ko_),                 \
        (AS3 unsigned int*)(dstA + bb_), 16, 0, 0);                                       \
    __builtin_amdgcn_global_load_lds((const AS1 unsigned int*)(gA + ko_ + 64 * K_DIM),    \
        (AS3 unsigned int*)(dstA + bb_ + 4096), 16, 0, 0);                                \
    __builtin_amdgcn_global_load_lds((const AS1 unsigned int*)(gB + ko_),                 \
        (AS3 unsigned int*)(dstB + bb_), 16, 0, 0);                                       \
    __builtin_amdgcn_global_load_lds((const AS1 unsigned int*)(gB + ko_ + 64 * K_DIM),    \
        (AS3 unsigned int*)(dstB + bb_ + 4096), 16, 0, 0);                                \
  } while (0)

    // frag read offsets (swizzled): row r, slot kg ^ ((r>>1)&3); frag step = 16
    // rows = +1024 B (swizzle-invariant).
    const int lrow = lane & 15;
    const int kg   = lane >> 4;            // 16B k-group 0..3
    const int rA   = wm * 64 + lrow;
    const int rB   = wn * 64 + lrow;
    const int offA0 = rA * 64 + ((kg ^ ((rA >> 1) & 3)) * 16);
    const int offB0 = rB * 64 + ((kg ^ ((rB >> 1) & 3)) * 16);

    i32x4 acc[4][4];
#pragma unroll
    for (int m = 0; m < 4; ++m)
#pragma unroll
        for (int n = 0; n < 4; ++n)
            acc[m][n] = (i32x4){0, 0, 0, 0};

#define MM(m_, n_, a_, b_) acc[m_][n_] = __builtin_amdgcn_mfma_i32_16x16x64_i8((a_), (b_), acc[m_][n_], 0, 0, 0)
#define BAR() do { __builtin_amdgcn_s_barrier(); asm volatile("" ::: "memory"); } while (0)
#define VMCNT0() asm volatile("s_waitcnt vmcnt(0)" ::: "memory")

    // prologue: tile 0 staged and certified
    STAGE(0);
    VMCNT0();
    BAR();

    for (int tt = 0; tt < NT; ++tt) {
        const char* bA = ldsA + (tt & 1) * 8192;
        const char* bB = ldsB + (tt & 1) * 8192;
        const bool pf = (tt + 1) < NT;

        if (pf) STAGE(tt + 1);

        i32x4 a0 = *(const i32x4*)(bA + offA0);
        i32x4 a1 = *(const i32x4*)(bA + offA0 + 1024);
        i32x4 a2 = *(const i32x4*)(bA + offA0 + 2048);
        i32x4 a3 = *(const i32x4*)(bA + offA0 + 3072);
        i32x4 b0 = *(const i32x4*)(bB + offB0);
        i32x4 b1 = *(const i32x4*)(bB + offB0 + 1024);
        i32x4 b2 = *(const i32x4*)(bB + offB0 + 2048);
        i32x4 b3 = *(const i32x4*)(bB + offB0 + 3072);

        __builtin_amdgcn_s_setprio(1);
        MM(0,0,a0,b0); MM(0,1,a0,b1); MM(0,2,a0,b2); MM(0,3,a0,b3);
        MM(1,0,a1,b0); MM(1,1,a1,b1); MM(1,2,a1,b2); MM(1,3,a1,b3);
        MM(2,0,a2,b0); MM(2,1,a2,b1); MM(2,2,a2,b2); MM(2,3,a2,b3);
        MM(3,0,a3,b0); MM(3,1,a3,b1); MM(3,2,a3,b2); MM(3,3,a3,b3);
        __builtin_amdgcn_s_setprio(0);

        if (pf) {
            VMCNT0();   // covered by this tile's reads+MFMA and the 3 other blocks
            BAR();      // certifies tile tt+1; reads of tt done -> stage(tt+2) safe
        }
    }
#undef STAGE
#undef MM
#undef BAR
#undef VMCNT0

    // epilogue: C/D layout col = lane&15, row = (lane>>4)*4 + j
    const int colq = lane & 15;
    const int rowq = lane >> 4;
#pragma unroll
    for (int n = 0; n < 4; ++n) {
        size_t col = bcol + wn * 64 + n * 16 + colq;
        float sc = oscale[col];
        float bi = obias[col];
#pragma unroll
        for (int m = 0; m < 4; ++m) {
            size_t rbase = brow + wm * 64 + m * 16 + (size_t)rowq * 4;
#pragma unroll
            for (int j = 0; j < 4; ++j)
                out[(rbase + j) * N_DIM + col] = (float)acc[m][n][j] * sc + bi;
        }
    }
}

extern "C" void kernel_launch(void* const* d_in, const int* in_sizes, int n_in,
                              void* d_out, int out_size, void* d_ws, size_t ws_size,
                              hipStream_t stream) {
    const float* x        = (const float*)d_in[0];
    const float* weight   = (const float*)d_in[1];
    const float* bias     = (const float*)d_in[2];
    const float* in_scale = (const float*)d_in[3];
    const float* w_scale  = (const float*)d_in[4];
    const float* b_scale  = (const float*)d_in[5];
    float* out = (float*)d_out;

    char* ws = (char*)d_ws;
    const size_t xk = (size_t)M_DIM * K_DIM;
    const size_t wk = (size_t)N_DIM * K_DIM;
    char*  qx     = ws;
    char*  qw     = ws + xk;
    float* oscale = (float*)(ws + xk + wk);
    float* obias  = oscale + N_DIM;

    quant_all_kernel<<<8224, 256, 0, stream>>>(x, weight, bias, in_scale, w_scale,
                                               b_scale, (i32x4*)qx, (i32x4*)qw,
                                               oscale, obias);
    gemm_i8_kernel<<<4096, 256, 0, stream>>>(qx, qw, oscale, obias, out);
}

// Round 16
// 217.199 us; speedup vs baseline: 1.1541x; 1.0070x over previous
//
#include <hip/hip_runtime.h>

typedef int i32x4 __attribute__((ext_vector_type(4)));

#define AS1 __attribute__((address_space(1)))
#define AS3 __attribute__((address_space(3)))

#define M_DIM 8192
#define N_DIM 8192
#define K_DIM 2048
#define NT 32   // K-tiles of 64 bytes

// ---------------- fused quantize: x (per-tensor), w (per-row), prep (scale+bias) -------
__global__ __launch_bounds__(256) void quant_all_kernel(
    const float* __restrict__ x, const float* __restrict__ w,
    const float* __restrict__ bias,
    const float* __restrict__ in_scale, const float* __restrict__ w_scale,
    const float* __restrict__ b_scale,
    i32x4* __restrict__ qx, i32x4* __restrict__ qw,
    float* __restrict__ oscale, float* __restrict__ obias)
{
    const int bid = blockIdx.x;
    if (bid < 8192) {
        const int idx = (bid & 4095) * 256 + threadIdx.x;   // 0..1048575
        const bool isx = bid < 4096;
        float s = isx ? in_scale[0] : w_scale[idx >> 7];
        const float4* p = reinterpret_cast<const float4*>(isx ? x : w) + (size_t)idx * 4;
        union { char c[16]; i32x4 v; } u;
#pragma unroll
        for (int v4 = 0; v4 < 4; ++v4) {
            float4 f = p[v4];
            u.c[v4*4+0] = (char)(int)fminf(fmaxf(rintf(f.x / s), -128.f), 127.f);
            u.c[v4*4+1] = (char)(int)fminf(fmaxf(rintf(f.y / s), -128.f), 127.f);
            u.c[v4*4+2] = (char)(int)fminf(fmaxf(rintf(f.z / s), -128.f), 127.f);
            u.c[v4*4+3] = (char)(int)fminf(fmaxf(rintf(f.w / s), -128.f), 127.f);
        }
        (isx ? qx : qw)[idx] = u.v;
    } else {
        const int i = (bid - 8192) * 256 + threadIdx.x;
        if (i < N_DIM) {
            oscale[i] = in_scale[0] * w_scale[i] * 0.5f;   // W_ALPHA
            float bs = b_scale[i];
            float q = fminf(fmaxf(rintf(bias[i] / bs), -128.f), 127.f);
            obias[i] = q * bs * 0.75f;                      // B_BETA
        }
    }
}

// ---------------- int8 GEMM: 128x128 tile, 4 waves of 64x64, 4 blocks/CU ----------------
// R15 frame (176us GEMM, best) + 3 micro-edits:
//  (1) ds_reads issued BEFORE stage(t+1): MFMA starts sooner; stage's LDS-writes
//      land during the MFMA phase when the read port is idle (less port contention).
//  (2) setprio removed (m190: hurts barrier-synced GEMM).
//  (3) 2-tile unroll, compile-time ring indices.
// Geometry/sync identical to R15: 4 blocks/CU (bounds(256,4), regs ~124, LDS 32KiB),
// column-stripe XCD swizzle (FETCH 99MB), R2-verified swizzle (0 conflicts),
// {reads; stage(t+1); MFMA; vmcnt(0); bar} per tile. Ring safety as R15.
__global__ __launch_bounds__(256, 4) void gemm_i8_kernel(
    const char* __restrict__ qx,   // [M][K] int8
    const char* __restrict__ qw,   // [N][K] int8
    const float* __restrict__ oscale,
    const float* __restrict__ obias,
    float* __restrict__ out)       // [M][N] fp32
{
    __shared__ __align__(16) char ldsA[2 * 8192];
    __shared__ __align__(16) char ldsB[2 * 8192];

    const int t    = threadIdx.x;          // 0..255
    const int lane = t & 63;
    const int wid  = t >> 6;               // 0..3
    const int wm   = wid >> 1;             // 0..1
    const int wn   = wid & 1;              // 0..1

    // XCD column-stripe swizzle (R12/R15-proven locality)
    int bid = blockIdx.x;                   // 4096 blocks
    int sl  = bid >> 3;                     // 0..511
    const size_t brow = (size_t)(sl >> 3) * 128;                    // 64 row-blocks
    const size_t bcol = (size_t)((bid & 7) * 8 + (sl & 7)) * 128;   // 64 col-blocks

    // staging: thread t covers row c*64 + t/4, 16B slot t&3 (linear dest);
    // global source pre-swizzled: logical slot = (t&3) ^ ((t>>3)&3)  (rule 21).
    const int srow  = t >> 2;              // 0..63
    const int lslot = (t & 3) ^ ((t >> 3) & 3);
    const char* gA = qx + (brow + srow) * K_DIM + lslot * 16;
    const char* gB = qw + (bcol + srow) * K_DIM + lslot * 16;
    char* dstA = ldsA + t * 16;
    char* dstB = ldsB + t * 16;

#define STAGE(tt_, bb_) do {                                                              \
    const int ko_ = (tt_) * 64;                                                           \
    __builtin_amdgcn_global_load_lds((const AS1 unsigned int*)(gA + ko_),                 \
        (AS3 unsigned int*)(dstA + (bb_) * 8192), 16, 0, 0);                              \
    __builtin_amdgcn_global_load_lds((const AS1 unsigned int*)(gA + ko_ + 64 * K_DIM),    \
        (AS3 unsigned int*)(dstA + (bb_) * 8192 + 4096), 16, 0, 0);                       \
    __builtin_amdgcn_global_load_lds((const AS1 unsigned int*)(gB + ko_),                 \
        (AS3 unsigned int*)(dstB + (bb_) * 8192), 16, 0, 0);                              \
    __builtin_amdgcn_global_load_lds((const AS1 unsigned int*)(gB + ko_ + 64 * K_DIM),    \
        (AS3 unsigned int*)(dstB + (bb_) * 8192 + 4096), 16, 0, 0);                       \
  } while (0)

    // frag read offsets (swizzled): row r, slot kg ^ ((r>>1)&3); frag step = +1024 B.
    const int lrow = lane & 15;
    const int kg   = lane >> 4;            // 16B k-group 0..3
    const int rA   = wm * 64 + lrow;
    const int rB   = wn * 64 + lrow;
    const int offA0 = rA * 64 + ((kg ^ ((rA >> 1) & 3)) * 16);
    const int offB0 = rB * 64 + ((kg ^ ((rB >> 1) & 3)) * 16);

    i32x4 acc[4][4];
#pragma unroll
    for (int m = 0; m < 4; ++m)
#pragma unroll
        for (int n = 0; n < 4; ++n)
            acc[m][n] = (i32x4){0, 0, 0, 0};

#define MM(m_, n_, a_, b_) acc[m_][n_] = __builtin_amdgcn_mfma_i32_16x16x64_i8((a_), (b_), acc[m_][n_], 0, 0, 0)
#define BAR() do { __builtin_amdgcn_s_barrier(); asm volatile("" ::: "memory"); } while (0)
#define VMCNT0() asm volatile("s_waitcnt vmcnt(0)" ::: "memory")

    // KT(tile, curbuf): reads first, then stage(t+1) into buf^1, MFMA, gate+bar.
#define KT(tt_, cb_, PF_) do {                                                            \
    const char* bA = ldsA + (cb_) * 8192;                                                 \
    const char* bB = ldsB + (cb_) * 8192;                                                 \
    i32x4 a0 = *(const i32x4*)(bA + offA0);                                               \
    i32x4 a1 = *(const i32x4*)(bA + offA0 + 1024);                                        \
    i32x4 a2 = *(const i32x4*)(bA + offA0 + 2048);                                        \
    i32x4 a3 = *(const i32x4*)(bA + offA0 + 3072);                                        \
    i32x4 b0 = *(const i32x4*)(bB + offB0);                                               \
    i32x4 b1 = *(const i32x4*)(bB + offB0 + 1024);                                        \
    i32x4 b2 = *(const i32x4*)(bB + offB0 + 2048);                                        \
    i32x4 b3 = *(const i32x4*)(bB + offB0 + 3072);                                        \
    if (PF_) STAGE((tt_) + 1, (cb_) ^ 1);                                                 \
    MM(0,0,a0,b0); MM(0,1,a0,b1); MM(0,2,a0,b2); MM(0,3,a0,b3);                           \
    MM(1,0,a1,b0); MM(1,1,a1,b1); MM(1,2,a1,b2); MM(1,3,a1,b3);                           \
    MM(2,0,a2,b0); MM(2,1,a2,b1); MM(2,2,a2,b2); MM(2,3,a2,b3);                           \
    MM(3,0,a3,b0); MM(3,1,a3,b1); MM(3,2,a3,b2); MM(3,3,a3,b3);                           \
    if (PF_) { VMCNT0(); BAR(); }                                                         \
  } while (0)

    // prologue: tile 0 staged and certified
    STAGE(0, 0);
    VMCNT0();
    BAR();

    for (int it = 0; it < 15; ++it) {      // tiles 0..29
        KT(2*it,     0, 1);
        KT(2*it + 1, 1, 1);
    }
    KT(30, 0, 1);   // stages tile 31
    KT(31, 1, 0);   // final tile, no prefetch/no trailing sync

#undef KT
#undef STAGE
#undef MM
#undef BAR
#undef VMCNT0

    // epilogue: C/D layout col = lane&15, row = (lane>>4)*4 + j
    const int colq = lane & 15;
    const int rowq = lane >> 4;
#pragma unroll
    for (int n = 0; n < 4; ++n) {
        size_t col = bcol + wn * 64 + n * 16 + colq;
        float sc = oscale[col];
        float bi = obias[col];
#pragma unroll
        for (int m = 0; m < 4; ++m) {
            size_t rbase = brow + wm * 64 + m * 16 + (size_t)rowq * 4;
#pragma unroll
            for (int j = 0; j < 4; ++j)
                out[(rbase + j) * N_DIM + col] = (float)acc[m][n][j] * sc + bi;
        }
    }
}

extern "C" void kernel_launch(void* const* d_in, const int* in_sizes, int n_in,
                              void* d_out, int out_size, void* d_ws, size_t ws_size,
                              hipStream_t stream) {
    const float* x        = (const float*)d_in[0];
    const float* weight   = (const float*)d_in[1];
    const float* bias     = (const float*)d_in[2];
    const float* in_scale = (const float*)d_in[3];
    const float* w_scale  = (const float*)d_in[4];
    const float* b_scale  = (const float*)d_in[5];
    float* out = (float*)d_out;

    char* ws = (char*)d_ws;
    const size_t xk = (size_t)M_DIM * K_DIM;
    const size_t wk = (size_t)N_DIM * K_DIM;
    char*  qx     = ws;
    char*  qw     = ws + xk;
    float* oscale = (float*)(ws + xk + wk);
    float* obias  = oscale + N_DIM;

    quant_all_kernel<<<8224, 256, 0, stream>>>(x, weight, bias, in_scale, w_scale,
                                               b_scale, (i32x4*)qx, (i32x4*)qw,
                                               oscale, obias);
    gemm_i8_kernel<<<4096, 256, 0, stream>>>(qx, qw, oscale, obias, out);
}